// Round 2
// baseline (743.962 us; speedup 1.0000x reference)
//
#include <hip/hip_runtime.h>
#include <hip/hip_bf16.h>

#define S_TOK 8192
#define DM    2048
#define DFF   8192
#define NE    8
#define CAP   1024

typedef __bf16 bf16_t;
typedef __bf16 bf16x8 __attribute__((ext_vector_type(8)));
typedef float  f32x4  __attribute__((ext_vector_type(4)));

// ---------------- Kernel 1: gate logits + argmax (f32, first-max tie-break) ----------
__global__ __launch_bounds__(256) void gate_argmax(const float* __restrict__ x,
                                                   const float* __restrict__ wg,
                                                   int* __restrict__ eidx) {
    int s = blockIdx.x;
    const float* row = x + (size_t)s * DM;
    float acc[8] = {0.f,0.f,0.f,0.f,0.f,0.f,0.f,0.f};
    for (int k = threadIdx.x; k < DM; k += 256) {
        float xv = row[k];
        const float4* wp = (const float4*)(wg + (size_t)k * NE);
        float4 w0 = wp[0], w1 = wp[1];
        acc[0] += xv * w0.x; acc[1] += xv * w0.y; acc[2] += xv * w0.z; acc[3] += xv * w0.w;
        acc[4] += xv * w1.x; acc[5] += xv * w1.y; acc[6] += xv * w1.z; acc[7] += xv * w1.w;
    }
#pragma unroll
    for (int off = 32; off > 0; off >>= 1) {
#pragma unroll
        for (int e = 0; e < 8; ++e) acc[e] += __shfl_down(acc[e], off, 64);
    }
    __shared__ float red[4][8];
    int lane = threadIdx.x & 63, wv = threadIdx.x >> 6;
    if (lane == 0) {
#pragma unroll
        for (int e = 0; e < 8; ++e) red[wv][e] = acc[e];
    }
    __syncthreads();
    if (threadIdx.x == 0) {
        float best = -3.4e38f; int bi = 0;
#pragma unroll
        for (int e = 0; e < 8; ++e) {
            float v = red[0][e] + red[1][e] + red[2][e] + red[3][e];
            if (v > best) { best = v; bi = e; }   // strict > keeps first index (np argmax)
        }
        eidx[s] = bi;
    }
}

// ---------------- Kernel 2: slot assignment — SINGLE WAVE, register-only ------------
// 64 lanes, no shared memory, no __syncthreads: nothing left to race.
// Order-preserving: token order = it*64 + lane; rank within wave via ballot&below.
__global__ __launch_bounds__(64) void scatter_slots(const int* __restrict__ eidx,
                                                    int* __restrict__ srcOf) {
    int lane = threadIdx.x;                                   // 0..63
    unsigned long long below = (lane == 0) ? 0ull : ((1ull << lane) - 1ull);

    for (int i = lane; i < NE * CAP; i += 64) srcOf[i] = -1;  // init all slots empty

    int cnt[NE] = {0,0,0,0,0,0,0,0};                          // static-indexed -> registers
    for (int it = 0; it < S_TOK / 64; ++it) {
        int s = it * 64 + lane;
        int e = eidx[s];
#pragma unroll
        for (int ex = 0; ex < NE; ++ex) {
            unsigned long long m = __ballot(e == ex);
            if (e == ex) {
                int loc = cnt[ex] + __popcll(m & below);
                if (loc < CAP) srcOf[ex * CAP + loc] = s;
            }
            cnt[ex] += __popcll(m);
        }
    }
}

// ---------------- Kernel 3: gather + f32->bf16, tile-ready layout -------------------
// abuf layout: tile t = slot>>7 (64 tiles of 128 rows). Per tile: [64 kt][128 m][32 k] bf16.
// byte addr = t*524288 + kt*8192 + m*64 + k*2
__global__ __launch_bounds__(256) void pack_rows(const float* __restrict__ x,
                                                 const int* __restrict__ srcOf,
                                                 bf16_t* __restrict__ abuf) {
    int slot = blockIdx.x;
    int t = slot >> 7, m = slot & 127;
    int src = srcOf[slot];
    int tid = threadIdx.x;
    int kt = tid >> 2, kq = tid & 3;
    bf16x8 v = {};
    if (src >= 0) {
        const float4* p = (const float4*)(x + (size_t)src * DM + kt * 32 + kq * 8);
        float4 a = p[0], b = p[1];
        v = bf16x8{(bf16_t)a.x,(bf16_t)a.y,(bf16_t)a.z,(bf16_t)a.w,
                   (bf16_t)b.x,(bf16_t)b.y,(bf16_t)b.z,(bf16_t)b.w};
    }
    *(bf16x8*)((char*)abuf + (size_t)t * 524288 + kt * 8192 + m * 64 + kq * 16) = v;
}

// ---------------- Kernel 4: per-expert GEMM, bf16 MFMA 16x16x32 ---------------------
#define BM 128
#define BN 128
#define BK 32
#define LDST 80   // LDS row stride in bytes (32 bf16 + 16B pad -> 2-way-max bank aliasing)

__device__ inline unsigned pack_bf16x2(float lo, float hi) {
    bf16_t l = (bf16_t)lo, h = (bf16_t)hi;
    return (unsigned)__builtin_bit_cast(unsigned short, l) |
           ((unsigned)__builtin_bit_cast(unsigned short, h) << 16);
}

__global__ __launch_bounds__(256, 2) void moe_gemm(const bf16_t* __restrict__ abuf,
                                                   const float* __restrict__ we,
                                                   const float* __restrict__ be,
                                                   float* __restrict__ out) {
    __shared__ uint4 aLds4[128 * LDST / 16];
    __shared__ uint4 bLds4[128 * LDST / 16];
    char* aLds = (char*)aLds4;
    char* bLds = (char*)bLds4;

    int bid = blockIdx.x;
    int e  = bid & 7;          // expert == XCD (bid%8) for L2 locality
    int r  = bid >> 3;
    int nt = r >> 3;           // 0..63
    int mt = r & 7;            // 0..7  (mtiles sharing a B panel are adjacent)
    int tid = threadIdx.x;
    int lane = tid & 63, wv = tid >> 6;
    int wm = wv >> 1, wn = wv & 1;          // wave -> 64x64 quadrant

    // A source: contiguous 8KB per K-step, thread reads bytes [tid*32, +32)
    const char* aSrc = (const char*)abuf + (size_t)(e * 8 + mt) * 524288 + (size_t)tid * 32;
    char* aW = aLds + (tid >> 1) * LDST + (tid & 1) * 32;

    // B source: rows k=2*kp, k=2*kp+1 ; cols nt*BN + n0 .. +8
    int kp = tid & 15;
    int n0 = (tid >> 4) * 8;
    const float* bSrc = we + ((size_t)e * DM + 2 * kp) * DFF + (size_t)nt * BN + n0;
    unsigned xw = (((unsigned)tid >> 4) & 3u) << 4;   // write-side XOR (within-row offset)

    // fragment read offsets (K-invariant)
    int g = lane >> 4, lr = lane & 15;
    int aOff[4], bOff[4];
#pragma unroll
    for (int i = 0; i < 4; ++i) {
        int mrow = wm * 64 + i * 16 + lr;
        aOff[i] = mrow * LDST + g * 16;
        int ncol = wn * 64 + i * 16 + lr;
        bOff[i] = ncol * LDST + (((unsigned)(g * 16)) ^ ((((unsigned)ncol >> 3) & 3u) << 4));
    }

    f32x4 acc[4][4];
#pragma unroll
    for (int i = 0; i < 4; ++i)
#pragma unroll
        for (int j = 0; j < 4; ++j) acc[i][j] = f32x4{0.f,0.f,0.f,0.f};

    for (int kt = 0; kt < DM / BK; ++kt) {
        // ---- stage A (bf16, already tile-ordered) ----
        {
            const uint4* p = (const uint4*)(aSrc + (size_t)kt * 8192);
            uint4 v0 = p[0], v1 = p[1];
            *(uint4*)aW        = v0;
            *(uint4*)(aW + 16) = v1;
        }
        // ---- stage B (f32 -> bf16 pairs, transposed [n][k]) ----
        {
            const float* bp = bSrc + (size_t)kt * BK * DFF;
            const float4* q0 = (const float4*)bp;
            const float4* q1 = (const float4*)(bp + DFF);
            float4 g0 = q0[0], g1 = q0[1];
            float4 h0 = q1[0], h1 = q1[1];
            float lo[8] = {g0.x,g0.y,g0.z,g0.w,g1.x,g1.y,g1.z,g1.w};
            float hi[8] = {h0.x,h0.y,h0.z,h0.w,h1.x,h1.y,h1.z,h1.w};
#pragma unroll
            for (int j = 0; j < 8; ++j) {
                unsigned pk = pack_bf16x2(lo[j], hi[j]);
                int n = n0 + j;
                *(unsigned*)(bLds + n * LDST + (((unsigned)(kp * 4)) ^ xw)) = pk;
            }
        }
        __syncthreads();
        // ---- MFMA phase ----
        bf16x8 af[4];
#pragma unroll
        for (int i = 0; i < 4; ++i) af[i] = *(const bf16x8*)(aLds + aOff[i]);
#pragma unroll
        for (int j = 0; j < 4; ++j) {
            bf16x8 bvv = *(const bf16x8*)(bLds + bOff[j]);
#pragma unroll
            for (int i = 0; i < 4; ++i)
                acc[i][j] = __builtin_amdgcn_mfma_f32_16x16x32_bf16(af[i], bvv, acc[i][j], 0, 0, 0);
        }
        __syncthreads();
    }

    // ---- epilogue: C/D layout col=lane&15, row=(lane>>4)*4+reg ----
    int orow0 = e * CAP + mt * BM + wm * 64 + (lane >> 4) * 4;
    int ocol0 = nt * BN + wn * 64 + (lane & 15);
#pragma unroll
    for (int j = 0; j < 4; ++j) {
        int oc = ocol0 + j * 16;
        float bias = be[(size_t)e * DFF + oc];
#pragma unroll
        for (int i = 0; i < 4; ++i) {
            int orow = orow0 + i * 16;
#pragma unroll
            for (int q = 0; q < 4; ++q)
                out[(size_t)(orow + q) * DFF + oc] = acc[i][j][q] + bias;
        }
    }
}

// ---------------- launcher ----------------------------------------------------------
extern "C" void kernel_launch(void* const* d_in, const int* in_sizes, int n_in,
                              void* d_out, int out_size, void* d_ws, size_t ws_size,
                              hipStream_t stream) {
    const float* x  = (const float*)d_in[0];
    const float* wg = (const float*)d_in[1];
    const float* we = (const float*)d_in[2];
    const float* be = (const float*)d_in[3];
    float* out = (float*)d_out;

    // workspace: [0,32KB) eidx, [32KB,64KB) srcOf, [64KB, 64KB+32MB) abuf
    size_t need = 65536 + (size_t)64 * 524288;
    if (ws_size < need) return;  // fail loudly (poisoned output) rather than corrupt

    int* eidx  = (int*)d_ws;
    int* srcOf = eidx + S_TOK;
    bf16_t* abuf = (bf16_t*)((char*)d_ws + 65536);

    gate_argmax<<<S_TOK, 256, 0, stream>>>(x, wg, eidx);
    scatter_slots<<<1, 64, 0, stream>>>(eidx, srcOf);
    pack_rows<<<S_TOK, 256, 0, stream>>>(x, srcOf, abuf);
    moe_gemm<<<NE * 8 * 64, 256, 0, stream>>>(abuf, we, be, out);
}

// Round 3
// 524.201 us; speedup vs baseline: 1.4192x; 1.4192x over previous
//
#include <hip/hip_runtime.h>
#include <hip/hip_bf16.h>

#define S_TOK 8192
#define DM    2048
#define DFF   8192
#define NE    8
#define CAP   1024

typedef __bf16 bf16_t;
typedef __bf16 bf16x8 __attribute__((ext_vector_type(8)));
typedef float  f32x4  __attribute__((ext_vector_type(4)));

__device__ __forceinline__ void load_lds16(const void* g, void* l) {
    __builtin_amdgcn_global_load_lds((const __attribute__((address_space(1))) void*)g,
                                     (__attribute__((address_space(3))) void*)l,
                                     16, 0, 0);
}

// ---------------- Kernel 1: gate logits + argmax — one wave per token ---------------
__global__ __launch_bounds__(256) void gate_argmax(const float* __restrict__ x,
                                                   const float* __restrict__ wg,
                                                   int* __restrict__ eidx) {
    int lane = threadIdx.x & 63, wv = threadIdx.x >> 6;
    int s = blockIdx.x * 4 + wv;
    const float* row = x + (size_t)s * DM;
    float acc[8] = {0.f,0.f,0.f,0.f,0.f,0.f,0.f,0.f};
    for (int kb = 0; kb < DM; kb += 256) {
        int k0 = kb + lane * 4;
        float4 xv = *(const float4*)(row + k0);
        const float* wr = wg + (size_t)k0 * NE;
        float xs[4] = {xv.x, xv.y, xv.z, xv.w};
#pragma unroll
        for (int c = 0; c < 4; ++c) {
            float4 w0 = *(const float4*)(wr + c * 8);
            float4 w1 = *(const float4*)(wr + c * 8 + 4);
            acc[0] += xs[c] * w0.x; acc[1] += xs[c] * w0.y;
            acc[2] += xs[c] * w0.z; acc[3] += xs[c] * w0.w;
            acc[4] += xs[c] * w1.x; acc[5] += xs[c] * w1.y;
            acc[6] += xs[c] * w1.z; acc[7] += xs[c] * w1.w;
        }
    }
#pragma unroll
    for (int off = 32; off > 0; off >>= 1)
#pragma unroll
        for (int e = 0; e < 8; ++e) acc[e] += __shfl_xor(acc[e], off, 64);
    if (lane == 0) {
        float best = acc[0]; int bi = 0;
#pragma unroll
        for (int e = 1; e < 8; ++e) if (acc[e] > best) { best = acc[e]; bi = e; }
        eidx[s] = bi;
    }
}

// ---------------- Kernel 2: slot assignment — single wave, prefetch-pipelined -------
__global__ __launch_bounds__(64) void scatter_slots(const int* __restrict__ eidx,
                                                    int* __restrict__ srcOf) {
    int lane = threadIdx.x;
    unsigned long long below = (lane == 0) ? 0ull : ((1ull << lane) - 1ull);
    for (int i = lane; i < NE * CAP; i += 64) srcOf[i] = -1;

    int cnt[NE] = {0,0,0,0,0,0,0,0};
    int e_cur = eidx[lane];
    for (int it = 0; it < S_TOK / 64; ++it) {
        int e_nxt = (it < S_TOK / 64 - 1) ? eidx[(it + 1) * 64 + lane] : 0;
        int s = it * 64 + lane;
#pragma unroll
        for (int ex = 0; ex < NE; ++ex) {
            unsigned long long m = __ballot(e_cur == ex);
            if (e_cur == ex) {
                int loc = cnt[ex] + __popcll(m & below);
                if (loc < CAP) srcOf[ex * CAP + loc] = s;
            }
            cnt[ex] += __popcll(m);
        }
        e_cur = e_nxt;
    }
}

// ---------------- Kernel 3: gather + f32->bf16 into PRE-SWIZZLED tile images --------
// abuf: per (e, mt, kt) a 32 KiB image of [256 m][64 k] bf16, row stride 128 B,
// byte addr within image = m*128 + ((kbyte) ^ ((m&7)<<4)).  gload_lds copies linearly.
__global__ __launch_bounds__(256) void pack_rows(const float* __restrict__ x,
                                                 const int* __restrict__ srcOf,
                                                 char* __restrict__ abuf) {
    int slot = blockIdx.x;               // e*1024 + c
    int e = slot >> 10, c = slot & 1023;
    int mt = c >> 8, m = c & 255;
    int src = srcOf[slot];
    int tid = threadIdx.x;
    int kt = tid >> 3, kg = tid & 7;     // kt 0..31, kg 0..7 (8 bf16 per 16 B)
    bf16x8 v = {};
    if (src >= 0) {
        const float4* p = (const float4*)(x + (size_t)src * DM + kt * 64 + kg * 8);
        float4 a = p[0], b = p[1];
        v = bf16x8{(bf16_t)a.x,(bf16_t)a.y,(bf16_t)a.z,(bf16_t)a.w,
                   (bf16_t)b.x,(bf16_t)b.y,(bf16_t)b.z,(bf16_t)b.w};
    }
    size_t img = ((size_t)((e * 4 + mt) * 32 + kt)) << 15;
    int off = m * 128 + ((kg * 16) ^ ((m & 7) << 4));
    *(bf16x8*)(abuf + img + off) = v;
}

// ---------------- Kernel 4: 256x256x64 bf16 MFMA GEMM, dbuf LDS, 4-phase ------------
__global__ __launch_bounds__(512, 2) void moe_gemm(const char* __restrict__ abuf,
                                                   const float* __restrict__ we,
                                                   const float* __restrict__ be,
                                                   float* __restrict__ out) {
    __shared__ uint4 smem4[131072 / 16];           // [buf][A 32K | B 32K]
    char* smem = (char*)smem4;

    int bid = blockIdx.x;
    int e  = bid & 7;                   // expert == XCD
    int r  = bid >> 3;
    int mt = r & 3;                     // 4 m-tiles of 256
    int nt = r >> 2;                    // 32 n-tiles of 256
    int tid = threadIdx.x, lane = tid & 63, wv = tid >> 6;
    int wm = wv >> 2, wn = wv & 3;      // 2x4 wave grid -> 128x64 per wave
    int lr = lane & 15, g = lane >> 4;

    const char* aImg = abuf + (((size_t)((e * 4 + mt) * 32)) << 15);
    const float* bBase = we + (size_t)e * DM * DFF + (size_t)nt * 256 + lane * 4;

    // swizzled fragment column offsets (row&7 == lr&7 for all frag rows)
    int colx[2];
    colx[0] = (((0 * 4 + g) ^ (lr & 7)) << 4);
    colx[1] = (((1 * 4 + g) ^ (lr & 7)) << 4);
    int aRow = wm * 128 + lr;           // + mfrag*16
    int bRow = wn * 64 + lr;            // + nfrag*16

    // B stage: wave wv loads k rows wv*8..+7, lane covers 4 consecutive n
    int stOff = tid * 16;               // A image copy offset (+ i*8192)

    f32x4 acc[8][4] = {};
    float bs[32];                       // staged B f32, static-indexed

    auto stage_issue = [&](int kt, int buf) {
        const float* bp = bBase + (size_t)(kt * 64 + wv * 8) * DFF;
#pragma unroll
        for (int j = 0; j < 8; ++j) {
            float4 t = *(const float4*)(bp + (size_t)j * DFF);
            bs[j * 4 + 0] = t.x; bs[j * 4 + 1] = t.y;
            bs[j * 4 + 2] = t.z; bs[j * 4 + 3] = t.w;
        }
        const char* src = aImg + ((size_t)kt << 15) + stOff;
        char* dst = smem + buf * 65536 + stOff;
#pragma unroll
        for (int i = 0; i < 4; ++i) load_lds16(src + i * 8192, dst + i * 8192);
    };

    auto stage_writeB = [&](int buf) {
        char* bL = smem + buf * 65536 + 32768;
#pragma unroll
        for (int i = 0; i < 4; ++i) {
            int n = lane * 4 + i;
            bf16x8 w;
#pragma unroll
            for (int j = 0; j < 8; ++j) w[j] = (bf16_t)bs[j * 4 + i];
            *(bf16x8*)(bL + n * 128 + ((wv * 16) ^ ((n & 7) << 4))) = w;
        }
    };

    // prologue: tile 0 into buf 0
    stage_issue(0, 0);
    stage_writeB(0);
    __syncthreads();

    for (int kt = 0; kt < 32; ++kt) {
        int cur = kt & 1, nxt = cur ^ 1;
        bool notlast = (kt < 31);
        if (notlast) stage_issue(kt + 1, nxt);

        const char* aC = smem + cur * 65536;
        const char* bC = aC + 32768;
#pragma unroll
        for (int mh = 0; mh < 2; ++mh) {
            bf16x8 af[4][2];
#pragma unroll
            for (int mf = 0; mf < 4; ++mf) {
                int rowm = aRow + (mh * 4 + mf) * 16;
                af[mf][0] = *(const bf16x8*)(aC + rowm * 128 + colx[0]);
                af[mf][1] = *(const bf16x8*)(aC + rowm * 128 + colx[1]);
            }
#pragma unroll
            for (int nh = 0; nh < 2; ++nh) {
                bf16x8 bf[2][2];
#pragma unroll
                for (int nf = 0; nf < 2; ++nf) {
                    int rown = bRow + (nh * 2 + nf) * 16;
                    bf[nf][0] = *(const bf16x8*)(bC + rown * 128 + colx[0]);
                    bf[nf][1] = *(const bf16x8*)(bC + rown * 128 + colx[1]);
                }
                __builtin_amdgcn_s_setprio(1);
#pragma unroll
                for (int mf = 0; mf < 4; ++mf)
#pragma unroll
                    for (int nf = 0; nf < 2; ++nf)
#pragma unroll
                        for (int kk = 0; kk < 2; ++kk)
                            acc[mh * 4 + mf][nh * 2 + nf] =
                                __builtin_amdgcn_mfma_f32_16x16x32_bf16(
                                    af[mf][kk], bf[nf][kk],
                                    acc[mh * 4 + mf][nh * 2 + nf], 0, 0, 0);
                __builtin_amdgcn_s_setprio(0);
            }
        }
        if (notlast) stage_writeB(nxt);
        __syncthreads();
    }

    // epilogue: C/D layout col=lane&15, row=(lane>>4)*4+q
    int orow0 = e * CAP + mt * 256 + wm * 128 + g * 4;
    int ocol0 = nt * 256 + wn * 64 + lr;
#pragma unroll
    for (int nf = 0; nf < 4; ++nf) {
        int oc = ocol0 + nf * 16;
        float bias = be[(size_t)e * DFF + oc];
#pragma unroll
        for (int mf = 0; mf < 8; ++mf) {
            int orow = orow0 + mf * 16;
#pragma unroll
            for (int q = 0; q < 4; ++q)
                out[(size_t)(orow + q) * DFF + oc] = acc[mf][nf][q] + bias;
        }
    }
}

// ---------------- launcher ----------------------------------------------------------
extern "C" void kernel_launch(void* const* d_in, const int* in_sizes, int n_in,
                              void* d_out, int out_size, void* d_ws, size_t ws_size,
                              hipStream_t stream) {
    const float* x  = (const float*)d_in[0];
    const float* wg = (const float*)d_in[1];
    const float* we = (const float*)d_in[2];
    const float* be = (const float*)d_in[3];
    float* out = (float*)d_out;

    size_t need = 65536 + (size_t)8 * 4 * 32 * 32768;   // 64 KB + 32 MB
    if (ws_size < need) return;

    int* eidx  = (int*)d_ws;
    int* srcOf = eidx + S_TOK;
    char* abuf = (char*)d_ws + 65536;

    gate_argmax<<<S_TOK / 4, 256, 0, stream>>>(x, wg, eidx);
    scatter_slots<<<1, 64, 0, stream>>>(eidx, srcOf);
    pack_rows<<<S_TOK, 256, 0, stream>>>(x, srcOf, abuf);
    moe_gemm<<<NE * 4 * 32, 512, 0, stream>>>(abuf, we, be, out);
}

// Round 4
// 500.337 us; speedup vs baseline: 1.4869x; 1.0477x over previous
//
#include <hip/hip_runtime.h>
#include <hip/hip_bf16.h>

#define S_TOK 8192
#define DM    2048
#define DFF   8192
#define NE    8
#define CAP   1024

typedef __bf16 bf16_t;
typedef __bf16 bf16x8 __attribute__((ext_vector_type(8)));
typedef float  f32x4  __attribute__((ext_vector_type(4)));

__device__ __forceinline__ void load_lds16(const void* g, void* l) {
    __builtin_amdgcn_global_load_lds((const __attribute__((address_space(1))) void*)g,
                                     (__attribute__((address_space(3))) void*)l,
                                     16, 0, 0);
}

// ---------------- Kernel 1: gate logits + argmax — one wave per token ---------------
__global__ __launch_bounds__(256) void gate_argmax(const float* __restrict__ x,
                                                   const float* __restrict__ wg,
                                                   int* __restrict__ eidx) {
    int lane = threadIdx.x & 63, wv = threadIdx.x >> 6;
    int s = blockIdx.x * 4 + wv;
    const float* row = x + (size_t)s * DM;
    float acc[8] = {0.f,0.f,0.f,0.f,0.f,0.f,0.f,0.f};
    for (int kb = 0; kb < DM; kb += 256) {
        int k0 = kb + lane * 4;
        float4 xv = *(const float4*)(row + k0);
        const float* wr = wg + (size_t)k0 * NE;
        float xs[4] = {xv.x, xv.y, xv.z, xv.w};
#pragma unroll
        for (int c = 0; c < 4; ++c) {
            float4 w0 = *(const float4*)(wr + c * 8);
            float4 w1 = *(const float4*)(wr + c * 8 + 4);
            acc[0] += xs[c] * w0.x; acc[1] += xs[c] * w0.y;
            acc[2] += xs[c] * w0.z; acc[3] += xs[c] * w0.w;
            acc[4] += xs[c] * w1.x; acc[5] += xs[c] * w1.y;
            acc[6] += xs[c] * w1.z; acc[7] += xs[c] * w1.w;
        }
    }
#pragma unroll
    for (int off = 32; off > 0; off >>= 1)
#pragma unroll
        for (int e = 0; e < 8; ++e) acc[e] += __shfl_xor(acc[e], off, 64);
    if (lane == 0) {
        float best = acc[0]; int bi = 0;
#pragma unroll
        for (int e = 1; e < 8; ++e) if (acc[e] > best) { best = acc[e]; bi = e; }
        eidx[s] = bi;
    }
}

// ---------------- Kernel 2: slot assignment — single wave, prefetch-pipelined -------
__global__ __launch_bounds__(64) void scatter_slots(const int* __restrict__ eidx,
                                                    int* __restrict__ srcOf) {
    int lane = threadIdx.x;
    unsigned long long below = (lane == 0) ? 0ull : ((1ull << lane) - 1ull);
    for (int i = lane; i < NE * CAP; i += 64) srcOf[i] = -1;

    int cnt[NE] = {0,0,0,0,0,0,0,0};
    int e_cur = eidx[lane];
    for (int it = 0; it < S_TOK / 64; ++it) {
        int e_nxt = (it < S_TOK / 64 - 1) ? eidx[(it + 1) * 64 + lane] : 0;
        int s = it * 64 + lane;
#pragma unroll
        for (int ex = 0; ex < NE; ++ex) {
            unsigned long long m = __ballot(e_cur == ex);
            if (e_cur == ex) {
                int loc = cnt[ex] + __popcll(m & below);
                if (loc < CAP) srcOf[ex * CAP + loc] = s;
            }
            cnt[ex] += __popcll(m);
        }
        e_cur = e_nxt;
    }
}

// ---------------- Kernel 3: gather + f32->bf16 into PRE-SWIZZLED tile images --------
// abuf: per (e, mt, kt) a 32 KiB image of [256 m][64 k] bf16, row stride 128 B,
// byte addr within image = m*128 + ((kbyte) ^ ((m&7)<<4)).  gload_lds copies linearly.
__global__ __launch_bounds__(256) void pack_rows(const float* __restrict__ x,
                                                 const int* __restrict__ srcOf,
                                                 char* __restrict__ abuf) {
    int slot = blockIdx.x;               // e*1024 + c
    int e = slot >> 10, c = slot & 1023;
    int mt = c >> 8, m = c & 255;
    int src = srcOf[slot];
    int tid = threadIdx.x;
    int kt = tid >> 3, kg = tid & 7;     // kt 0..31, kg 0..7 (8 bf16 per 16 B)
    bf16x8 v = {};
    if (src >= 0) {
        const float4* p = (const float4*)(x + (size_t)src * DM + kt * 64 + kg * 8);
        float4 a = p[0], b = p[1];
        v = bf16x8{(bf16_t)a.x,(bf16_t)a.y,(bf16_t)a.z,(bf16_t)a.w,
                   (bf16_t)b.x,(bf16_t)b.y,(bf16_t)b.z,(bf16_t)b.w};
    }
    size_t img = ((size_t)((e * 4 + mt) * 32 + kt)) << 15;
    int off = m * 128 + ((kg * 16) ^ ((m & 7) << 4));
    *(bf16x8*)(abuf + img + off) = v;
}

// ---------------- Kernel 4: 256x256x64 bf16 MFMA GEMM, dbuf, double-pumped B --------
__global__ __launch_bounds__(512, 2) void moe_gemm(const char* __restrict__ abuf,
                                                   const float* __restrict__ we,
                                                   const float* __restrict__ be,
                                                   float* __restrict__ out) {
    __shared__ uint4 smem4[131072 / 16];           // [buf][A 32K | B 32K]
    char* smem = (char*)smem4;

    int bid = blockIdx.x;
    int e  = bid & 7;                   // expert == XCD
    int r  = bid >> 3;
    int mt = r & 3;
    int nt = r >> 2;
    int tid = threadIdx.x, lane = tid & 63, wv = tid >> 6;
    int wm = wv >> 2, wn = wv & 3;      // 2x4 wave grid -> 128x64 per wave
    int lr = lane & 15, g = lane >> 4;

    const char* aImg = abuf + (((size_t)((e * 4 + mt) * 32)) << 15);
    const float* bBase = we + (size_t)e * DM * DFF + (size_t)nt * 256 + lane * 4;
    int stOff = tid * 16;

    f32x4 acc[8][4] = {};
    float bs[16];                       // staged B f32 — ONE half-tile (4 k-rows x 4 n)

    // issue 4 float4 loads for half h of K-tile kt (k rows wv*8 + h*4 .. +3)
    auto issueB = [&](int kt, int h) {
        const float* bp = bBase + (size_t)(kt * 64 + wv * 8 + h * 4) * DFF;
#pragma unroll
        for (int j = 0; j < 4; ++j) {
            float4 t = *(const float4*)(bp + (size_t)j * DFF);
            bs[j * 4 + 0] = t.x; bs[j * 4 + 1] = t.y;
            bs[j * 4 + 2] = t.z; bs[j * 4 + 3] = t.w;
        }
    };
    auto issueA = [&](int kt, int buf) {
        const char* src = aImg + ((size_t)kt << 15) + stOff;
        char* dst = smem + buf * 65536 + stOff;
#pragma unroll
        for (int i = 0; i < 4; ++i) load_lds16(src + i * 8192, dst + i * 8192);
    };
    // write half h: per n-row a b64 (4 k-values as bf16), slot-swizzled
    auto writeB = [&](int buf, int h) {
        char* bL = smem + buf * 65536 + 32768;
#pragma unroll
        for (int i = 0; i < 4; ++i) {
            int n = lane * 4 + i;
            ushort w[4];
#pragma unroll
            for (int j = 0; j < 4; ++j) {
                bf16_t b = (bf16_t)bs[j * 4 + i];
                w[j] = __builtin_bit_cast(unsigned short, b);
            }
            uint2 pk = { (unsigned)w[0] | ((unsigned)w[1] << 16),
                         (unsigned)w[2] | ((unsigned)w[3] << 16) };
            int slot = (n & 7) ^ ((n >> 3) & 7);
            *(uint2*)(bL + n * 128 + (((unsigned)(wv ^ slot)) << 4) + h * 8) = pk;
        }
    };

    // prologue: tile 0 into buf 0
    issueA(0, 0);
    issueB(0, 0); writeB(0, 0);
    issueB(0, 1); writeB(0, 1);
    __syncthreads();

    int aRow = wm * 128 + lr;
    int bRow = wn * 64 + lr;
    int xa = lr & 7;

    for (int kt = 0; kt < 32; ++kt) {
        int cur = kt & 1, nxt = cur ^ 1;
        bool notlast = (kt < 31);
        const char* aC = smem + cur * 65536;
        const char* bC = aC + 32768;

        if (notlast) { issueA(kt + 1, nxt); issueB(kt + 1, 0); }
        __builtin_amdgcn_sched_barrier(0);   // pin: prefetch issues stay at iter top

#pragma unroll
        for (int mh = 0; mh < 2; ++mh) {
            bf16x8 af[4][2];
#pragma unroll
            for (int mf = 0; mf < 4; ++mf) {
                int rowm = aRow + (mh * 4 + mf) * 16;
#pragma unroll
                for (int kk = 0; kk < 2; ++kk)
                    af[mf][kk] = *(const bf16x8*)(aC + rowm * 128 + (((kk * 4 + g) ^ xa) << 4));
            }
#pragma unroll
            for (int nh = 0; nh < 2; ++nh) {
                bf16x8 bfr[2][2];
#pragma unroll
                for (int nf = 0; nf < 2; ++nf) {
                    int rown = bRow + (nh * 2 + nf) * 16;
                    int xb = (rown & 7) ^ ((rown >> 3) & 7);
#pragma unroll
                    for (int kk = 0; kk < 2; ++kk)
                        bfr[nf][kk] = *(const bf16x8*)(bC + rown * 128 + (((kk * 4 + g) ^ xb) << 4));
                }
                __builtin_amdgcn_s_setprio(1);
#pragma unroll
                for (int mf = 0; mf < 4; ++mf)
#pragma unroll
                    for (int nf = 0; nf < 2; ++nf)
#pragma unroll
                        for (int kk = 0; kk < 2; ++kk)
                            acc[mh * 4 + mf][nh * 2 + nf] =
                                __builtin_amdgcn_mfma_f32_16x16x32_bf16(
                                    af[mf][kk], bfr[nf][kk],
                                    acc[mh * 4 + mf][nh * 2 + nf], 0, 0, 0);
                __builtin_amdgcn_s_setprio(0);
            }
            // after first half's MFMAs: retire B half-0, launch B half-1
            if (mh == 0 && notlast) { writeB(nxt, 0); issueB(kt + 1, 1); }
        }
        if (notlast) writeB(nxt, 1);
        __syncthreads();
    }

    // epilogue: C/D layout col=lane&15, row=(lane>>4)*4+q
    int orow0 = e * CAP + mt * 256 + wm * 128 + g * 4;
    int ocol0 = nt * 256 + wn * 64 + lr;
#pragma unroll
    for (int nf = 0; nf < 4; ++nf) {
        int oc = ocol0 + nf * 16;
        float bias = be[(size_t)e * DFF + oc];
#pragma unroll
        for (int mf = 0; mf < 8; ++mf) {
            int orow = orow0 + mf * 16;
#pragma unroll
            for (int q = 0; q < 4; ++q)
                out[(size_t)(orow + q) * DFF + oc] = acc[mf][nf][q] + bias;
        }
    }
}

// ---------------- launcher ----------------------------------------------------------
extern "C" void kernel_launch(void* const* d_in, const int* in_sizes, int n_in,
                              void* d_out, int out_size, void* d_ws, size_t ws_size,
                              hipStream_t stream) {
    const float* x  = (const float*)d_in[0];
    const float* wg = (const float*)d_in[1];
    const float* we = (const float*)d_in[2];
    const float* be = (const float*)d_in[3];
    float* out = (float*)d_out;

    size_t need = 65536 + (size_t)8 * 4 * 32 * 32768;   // 64 KB + 32 MB
    if (ws_size < need) return;

    int* eidx  = (int*)d_ws;
    int* srcOf = eidx + S_TOK;
    char* abuf = (char*)d_ws + 65536;

    gate_argmax<<<S_TOK / 4, 256, 0, stream>>>(x, wg, eidx);
    scatter_slots<<<1, 64, 0, stream>>>(eidx, srcOf);
    pack_rows<<<S_TOK, 256, 0, stream>>>(x, srcOf, abuf);
    moe_gemm<<<NE * 4 * 32, 512, 0, stream>>>(abuf, we, be, out);
}